// Round 7
// baseline (441.544 us; speedup 1.0000x reference)
//
#include <hip/hip_runtime.h>
#include <hip/hip_bf16.h>
#include <math.h>

typedef __hip_bfloat16 bf16;
typedef __attribute__((ext_vector_type(8))) __bf16 bf16x8;
typedef __attribute__((ext_vector_type(4))) float f32x4;

#define F_IN 64
#define KNB 6

// ws float offsets (fp32 weights + flags); staged xp/xs start at float 16384
#define WOFF_WP   0      // 2048
#define WOFF_BP   2048   // 32
#define WOFF_WE1  2080   // 6336
#define WOFF_BE1  8416   // 32
#define WOFF_WE2  8448   // 1024
#define WOFF_BE2  9472   // 32
#define WOFF_WE3  9504   // 192
#define WOFF_BE3  9696   // 6
#define WOFF_WS1  9728   // 2048
#define WOFF_BS1  11776  // 32
#define WOFF_WS2  11808  // 1024
#define WOFF_BS2  12832  // 32
#define WOFF_WS3  12864  // 32
#define WOFF_BS3  12896  // 1
#define FLAGS_OFF 13056  // int[2]: {is_bf16, is_int64}
#define WOFF_WSUM 13312  // 1024
#define WOFF_WDSQ 14336  // 192
#define STAGE_OFF 16384  // floats; then xp bf16 rows, then xs fp32

__device__ __forceinline__ float b2f(bf16 v) { return __bfloat162float(v); }
// fast ELU via hardware exp2; abs err ~1e-7 near 0, far under tol
__device__ __forceinline__ float eluf(float v) { return v > 0.f ? v : __expf(v) - 1.f; }

__device__ __forceinline__ ushort f2bu(float v) {
  __bf16 b = (__bf16)v; ushort u; __builtin_memcpy(&u, &b, 2); return u;
}

union U8 { uint4 u; bf16x8 v; ushort s[8]; };

// wave-private LDS write->read fence: wait lgkmcnt(0) only (keep vmcnt in flight)
__device__ __forceinline__ void lds_fence() {
  __builtin_amdgcn_wave_barrier();
  __builtin_amdgcn_s_waitcnt(0xC07F);
  __builtin_amdgcn_wave_barrier();
}

// ==================== setup: flags + weight staging + derived weights ====================
__global__ void setupK(const ushort* xb, const int* ni,
                       const void* Wp, const void* bp, const void* We1, const void* be1,
                       const void* We2, const void* be2, const void* We3, const void* be3,
                       const void* Ws1, const void* bs1, const void* Ws2, const void* bs2,
                       const void* Ws3, const void* bs3, float* w) {
  __shared__ int sbf;
  int t = threadIdx.x;
  if (t < 64) {
    // fp32 bits read as bf16 pairs -> ~47% of halves are |v|>100 or NaN; bf16 N(0,1) never
    int bad = 0;
    for (int i = t; i < 256; i += 64) {
      float v = __uint_as_float(((unsigned)xb[i]) << 16);
      if (!(fabsf(v) < 100.f)) bad++;
    }
    unsigned long long bm = __ballot(bad > 0);
    unsigned long long hm = __ballot(ni[2 * t + 1] != 0);
    if (t == 0) {
      int isbf = (__popcll(bm) < 4) ? 1 : 0;
      ((int*)(w + FLAGS_OFF))[0] = isbf;
      ((int*)(w + FLAGS_OFF))[1] = (hm == 0ULL) ? 1 : 0;
      sbf = isbf;
    }
  }
  __syncthreads();
  int bf = sbf;
  const void* srcs[14] = {Wp, bp, We1, be1, We2, be2, We3, be3, Ws1, bs1, Ws2, bs2, Ws3, bs3};
  const int sizes[14] = {2048, 32, 6336, 32, 1024, 32, 192, 6, 2048, 32, 1024, 32, 32, 1};
  const int offs[14] = {WOFF_WP, WOFF_BP, WOFF_WE1, WOFF_BE1, WOFF_WE2, WOFF_BE2, WOFF_WE3,
                        WOFF_BE3, WOFF_WS1, WOFF_BS1, WOFF_WS2, WOFF_BS2, WOFF_WS3, WOFF_BS3};
  for (int tt = 0; tt < 14; tt++) {
    const void* s = srcs[tt];
    int nel = sizes[tt];
    float* d = w + offs[tt];
    for (int i = t; i < nel; i += blockDim.x)
      d[i] = bf ? b2f(((const bf16*)s)[i]) : ((const float*)s)[i];
  }
  __syncthreads();
  for (int i = t; i < 1024; i += blockDim.x) {
    int j = i >> 5, o = i & 31;
    float s = 0.f;
    for (int k = 0; k < KNB; k++) s += w[WOFF_WE1 + (k * 33 + j) * 32 + o];
    w[WOFF_WSUM + i] = s;
  }
  for (int i = t; i < 192; i += blockDim.x) {
    int k = i >> 5, o = i & 31;
    w[WOFF_WDSQ + i] = w[WOFF_WE1 + (k * 33 + 32) * 32 + o];
  }
}

// B-fragment builder (fp32 ws): lane(n=lane&15) holds B[k=quad*8+j][n] = sgn*W[k*ld+n]
__device__ __forceinline__ bf16x8 bfrag(const float* W, int ld, int nValid, int kValid, float sgn) {
  int lane = threadIdx.x & 63;
  int n = lane & 15, quad = lane >> 4;
  bf16x8 r;
#pragma unroll
  for (int j = 0; j < 8; j++) {
    int k = quad * 8 + j;
    float v = (n < nValid && k < kValid) ? sgn * W[k * ld + n] : 0.f;
    r[j] = (__bf16)v;
  }
  return r;
}

// JIT fragment read from LDS image; volatile so it is NEVER hoisted into registers
__device__ __forceinline__ U8 readFrag(const uint4* s, int f) {
  int lane = threadIdx.x & 63;
  const volatile unsigned long long* p =
      (const volatile unsigned long long*)(s + ((f << 6) + lane));
  unsigned long long lo = p[0];
  unsigned long long hi = p[1];
  U8 r;
  r.u.x = (unsigned)lo; r.u.y = (unsigned)(lo >> 32);
  r.u.z = (unsigned)hi; r.u.w = (unsigned)(hi >> 32);
  return r;
}

// A-fragment from a 64-wide feature row: lane(m=lane&15) holds row[k0+quad*8+j]
template <bool BF16>
__device__ __forceinline__ bf16x8 afrag_row(const void* base, long row, int k0) {
  int quad = (threadIdx.x & 63) >> 4;
  if (BF16) {
    U8 u;
    u.u = *(const uint4*)((const ushort*)base + row * F_IN + k0 + quad * 8);
    return u.v;
  } else {
    const float* p = (const float*)base + row * F_IN + k0 + quad * 8;
    float4 a = *(const float4*)p, b = *(const float4*)(p + 4);
    bf16x8 r;
    r[0] = (__bf16)a.x; r[1] = (__bf16)a.y; r[2] = (__bf16)a.z; r[3] = (__bf16)a.w;
    r[4] = (__bf16)b.x; r[5] = (__bf16)b.y; r[6] = (__bf16)b.z; r[7] = (__bf16)b.w;
    return r;
  }
}

// ==================== kernel A: pre-dense + self MLP ====================
// frag ids: 0..1 fwp[0][t], 2..3 fwp[1][t], 4..5 fws1[0][t], 6..7 fws1[1][t],
//           8..9 fws2[t], 10 fws3
template <bool BF16>
__device__ void pre_tiles(const void* xv, const float* __restrict__ w,
                          ushort* __restrict__ xp, float* __restrict__ xs,
                          int n_nodes, const uint4* sfrag, ushort* buf) {
  int lane = threadIdx.x & 63;
  int m = lane & 15, quad = lane >> 4;

  float bpv[2], bs1v[2], bs2v[2];
#pragma unroll
  for (int t = 0; t < 2; t++) {
    bpv[t]  = w[WOFF_BP  + m + 16 * t];
    bs1v[t] = w[WOFF_BS1 + m + 16 * t];
    bs2v[t] = w[WOFF_BS2 + m + 16 * t];
  }
  float bs3f = w[WOFF_BS3];

  int T = (n_nodes + 15) >> 4;
  int wid = (int)((blockIdx.x * blockDim.x + threadIdx.x) >> 6);
  int nw = (int)((gridDim.x * blockDim.x) >> 6);
  f32x4 zero = {0.f, 0.f, 0.f, 0.f};

  for (int t0 = wid; t0 < T; t0 += nw) {
    long n0 = (long)t0 * 16;
    long row = n0 + m; if (row >= n_nodes) row = n_nodes - 1;
    bf16x8 a0 = afrag_row<BF16>(xv, row, 0);
    bf16x8 a1 = afrag_row<BF16>(xv, row, 32);
    f32x4 accp[2], accs[2];
    U8 f;
#pragma unroll
    for (int t = 0; t < 2; t++) {
      f = readFrag(sfrag, 0 + t); accp[t] = __builtin_amdgcn_mfma_f32_16x16x32_bf16(a0, f.v, zero, 0, 0, 0);
      f = readFrag(sfrag, 2 + t); accp[t] = __builtin_amdgcn_mfma_f32_16x16x32_bf16(a1, f.v, accp[t], 0, 0, 0);
      f = readFrag(sfrag, 4 + t); accs[t] = __builtin_amdgcn_mfma_f32_16x16x32_bf16(a0, f.v, zero, 0, 0, 0);
      f = readFrag(sfrag, 6 + t); accs[t] = __builtin_amdgcn_mfma_f32_16x16x32_bf16(a1, f.v, accs[t], 0, 0, 0);
    }
    // xp = elu(pre): C-layout -> LDS bf16 -> row layout -> global
#pragma unroll
    for (int t = 0; t < 2; t++)
#pragma unroll
      for (int r = 0; r < 4; r++)
        buf[(quad * 4 + r) * 32 + m + 16 * t] = f2bu(eluf(accp[t][r] + bpv[t]));
    lds_fence();
    {
      uint4 rv = *(const uint4*)(buf + m * 32 + quad * 8);
      *(uint4*)(xp + row * 32 + quad * 8) = rv;
    }
    // s1 -> LDS -> A-frag
#pragma unroll
    for (int t = 0; t < 2; t++)
#pragma unroll
      for (int r = 0; r < 4; r++)
        buf[(quad * 4 + r) * 32 + m + 16 * t] = f2bu(eluf(accs[t][r] + bs1v[t]));
    lds_fence();
    U8 as1; as1.u = *(const uint4*)(buf + m * 32 + quad * 8);
    f32x4 acc2[2];
#pragma unroll
    for (int t = 0; t < 2; t++) {
      f = readFrag(sfrag, 8 + t);
      acc2[t] = __builtin_amdgcn_mfma_f32_16x16x32_bf16(as1.v, f.v, zero, 0, 0, 0);
    }
#pragma unroll
    for (int t = 0; t < 2; t++)
#pragma unroll
      for (int r = 0; r < 4; r++)
        buf[(quad * 4 + r) * 32 + m + 16 * t] = f2bu(eluf(acc2[t][r] + bs2v[t]));
    lds_fence();
    U8 as2; as2.u = *(const uint4*)(buf + m * 32 + quad * 8);
    f = readFrag(sfrag, 10);
    f32x4 accx = __builtin_amdgcn_mfma_f32_16x16x32_bf16(as2.v, f.v, zero, 0, 0, 0);
    if (m == 0) {
#pragma unroll
      for (int r = 0; r < 4; r++) {
        long orow = n0 + quad * 4 + r;
        if (orow < n_nodes) xs[orow] = accx[r] + bs3f;
      }
    }
    lds_fence();  // protect buf before next iteration overwrites
  }
}

__launch_bounds__(256, 6)
__global__ void preK(const void* xv, const float* __restrict__ w,
                     const int* __restrict__ flags,
                     ushort* __restrict__ xp, float* __restrict__ xs, int n_nodes) {
  __shared__ uint4 sfrag[11 * 64];
  __shared__ ushort sb[4 * 512];
  if (threadIdx.x < 64) {
    int ln = threadIdx.x;
    U8 tmp;
#pragma unroll
    for (int t = 0; t < 2; t++) {
      tmp.v = bfrag(w + WOFF_WP  + 16 * t,        32, 16, 32, 1.f); sfrag[(0 + t) * 64 + ln] = tmp.u;
      tmp.v = bfrag(w + WOFF_WP  + 1024 + 16 * t, 32, 16, 32, 1.f); sfrag[(2 + t) * 64 + ln] = tmp.u;
      tmp.v = bfrag(w + WOFF_WS1 + 16 * t,        32, 16, 32, 1.f); sfrag[(4 + t) * 64 + ln] = tmp.u;
      tmp.v = bfrag(w + WOFF_WS1 + 1024 + 16 * t, 32, 16, 32, 1.f); sfrag[(6 + t) * 64 + ln] = tmp.u;
      tmp.v = bfrag(w + WOFF_WS2 + 16 * t,        32, 16, 32, 1.f); sfrag[(8 + t) * 64 + ln] = tmp.u;
    }
    tmp.v = bfrag(w + WOFF_WS3, 1, 1, 32, 1.f); sfrag[10 * 64 + ln] = tmp.u;
  }
  __syncthreads();
  ushort* buf = sb + (threadIdx.x >> 6) * 512;
  if (flags[0]) pre_tiles<true>(xv, w, xp, xs, n_nodes, sfrag, buf);
  else          pre_tiles<false>(xv, w, xp, xs, n_nodes, sfrag, buf);
}

// ==================== kernel B: edge MLP + softmax ====================
// frag ids: 0..1 fsum[t], 2+k*2+t fwe1[k][t] (2..13), 14..15 fdsq[t],
//           16..17 fwe2[t], 18 fwe3
template <bool BF16>
__device__ void edge_tiles(const ushort* __restrict__ xp, const float* __restrict__ xs,
                           const void* dsv, const int* __restrict__ ni, int i64,
                           const float* __restrict__ w, void* outv, int n_nodes,
                           const uint4* sfrag, ushort* buf, float* lbuf) {
  int lane = threadIdx.x & 63;
  int m = lane & 15, quad = lane >> 4;

  float be1v[2], be2v[2];
#pragma unroll
  for (int t = 0; t < 2; t++) {
    be1v[t] = w[WOFF_BE1 + m + 16 * t];
    be2v[t] = w[WOFF_BE2 + m + 16 * t];
  }
  float be3v = (m < 6) ? w[WOFF_BE3 + m] : 0.f;

  int T = (n_nodes + 15) >> 4;
  int wid = (int)((blockIdx.x * blockDim.x + threadIdx.x) >> 6);
  int nw = (int)((gridDim.x * blockDim.x) >> 6);
  f32x4 zero = {0.f, 0.f, 0.f, 0.f};

  for (int t0 = wid; t0 < T; t0 += nw) {
    long n0 = (long)t0 * 16;
    long row = n0 + m; if (row >= n_nodes) row = n_nodes - 1;

    int idxs[KNB];
#pragma unroll
    for (int k = 0; k < KNB; k++)
      idxs[k] = i64 ? ni[(row * KNB + k) * 2] : ni[row * KNB + k];

    U8 own; own.u = *(const uint4*)(xp + row * 32 + quad * 8);
    U8 nb[KNB];
#pragma unroll
    for (int k = 0; k < KNB; k++) {
      long ai = idxs[k];
      if (ai < 0 || ai >= n_nodes) ai = 0;
      nb[k].u = *(const uint4*)(xp + ai * 32 + quad * 8);
      if (idxs[k] < 0) { nb[k].u.x = 0; nb[k].u.y = 0; nb[k].u.z = 0; nb[k].u.w = 0; }
    }

    // dsq A-frag: A[m][k]=distsq[m][k] (k<6); only quad 0 holds data
    U8 ad; ad.u.x = 0; ad.u.y = 0; ad.u.z = 0; ad.u.w = 0;
    if (quad == 0) {
      if (BF16) {
        const unsigned* dp = (const unsigned*)dsv;
        ad.u.x = dp[row * 3 + 0];
        ad.u.y = dp[row * 3 + 1];
        ad.u.z = dp[row * 3 + 2];
      } else {
        const float* dp = (const float*)dsv + row * KNB;
#pragma unroll
        for (int k = 0; k < KNB; k++) ad.s[k] = f2bu(dp[k]);
      }
    }
    float xsv = xs[row];

    // h1 = -sum_k nb_k@Wk + dsq@Wdsq + own@Wsum (fragments streamed from LDS)
    f32x4 accA[2], accB[2];
    U8 f;
#pragma unroll
    for (int t = 0; t < 2; t++) {
      f = readFrag(sfrag, 2 + 0 * 2 + t); accA[t] = __builtin_amdgcn_mfma_f32_16x16x32_bf16(nb[0].v, f.v, zero, 0, 0, 0);
      f = readFrag(sfrag, 2 + 1 * 2 + t); accA[t] = __builtin_amdgcn_mfma_f32_16x16x32_bf16(nb[1].v, f.v, accA[t], 0, 0, 0);
      f = readFrag(sfrag, 2 + 2 * 2 + t); accA[t] = __builtin_amdgcn_mfma_f32_16x16x32_bf16(nb[2].v, f.v, accA[t], 0, 0, 0);
      f = readFrag(sfrag, 2 + 3 * 2 + t); accB[t] = __builtin_amdgcn_mfma_f32_16x16x32_bf16(nb[3].v, f.v, zero, 0, 0, 0);
      f = readFrag(sfrag, 2 + 4 * 2 + t); accB[t] = __builtin_amdgcn_mfma_f32_16x16x32_bf16(nb[4].v, f.v, accB[t], 0, 0, 0);
      f = readFrag(sfrag, 2 + 5 * 2 + t); accB[t] = __builtin_amdgcn_mfma_f32_16x16x32_bf16(nb[5].v, f.v, accB[t], 0, 0, 0);
      f = readFrag(sfrag, 14 + t);        accB[t] = __builtin_amdgcn_mfma_f32_16x16x32_bf16(ad.v, f.v, accB[t], 0, 0, 0);
      f = readFrag(sfrag, 0 + t);         accA[t] = __builtin_amdgcn_mfma_f32_16x16x32_bf16(own.v, f.v, accA[t], 0, 0, 0);
    }

    // elu -> LDS -> A-frag
#pragma unroll
    for (int t = 0; t < 2; t++)
#pragma unroll
      for (int r = 0; r < 4; r++)
        buf[(quad * 4 + r) * 32 + m + 16 * t] =
            f2bu(eluf(accA[t][r] + accB[t][r] + be1v[t]));
    lds_fence();
    U8 a1; a1.u = *(const uint4*)(buf + m * 32 + quad * 8);
    f32x4 acc2[2];
#pragma unroll
    for (int t = 0; t < 2; t++) {
      f = readFrag(sfrag, 16 + t);
      acc2[t] = __builtin_amdgcn_mfma_f32_16x16x32_bf16(a1.v, f.v, zero, 0, 0, 0);
    }
#pragma unroll
    for (int t = 0; t < 2; t++)
#pragma unroll
      for (int r = 0; r < 4; r++)
        buf[(quad * 4 + r) * 32 + m + 16 * t] = f2bu(eluf(acc2[t][r] + be2v[t]));
    lds_fence();
    U8 a2; a2.u = *(const uint4*)(buf + m * 32 + quad * 8);
    f = readFrag(sfrag, 18);
    f32x4 acc3 = __builtin_amdgcn_mfma_f32_16x16x32_bf16(a2.v, f.v, zero, 0, 0, 0);

    if (m < 6) {
#pragma unroll
      for (int r = 0; r < 4; r++) lbuf[(quad * 4 + r) * 8 + m] = acc3[r] + be3v;
    }
    lds_fence();
    if (lane < 16) {
      long nodeid = n0 + lane;
      if (nodeid < n_nodes) {
        float lg[7];
        lg[0] = xsv;  // row == nodeid for lanes 0..15
#pragma unroll
        for (int i = 0; i < 6; i++) lg[1 + i] = lbuf[lane * 8 + i];
        float mx = lg[0];
#pragma unroll
        for (int i = 1; i < 7; i++) mx = fmaxf(mx, lg[i]);
        float e[7], ssum = 0.f;
#pragma unroll
        for (int i = 0; i < 7; i++) { e[i] = __expf(lg[i] - mx); ssum += e[i]; }
        float inv = 1.f / ssum;
        if (BF16) {
          ushort* o = (ushort*)outv + nodeid * 7;
#pragma unroll
          for (int i = 0; i < 7; i++) o[i] = f2bu(e[i] * inv);
        } else {
          float* o = (float*)outv + nodeid * 7;
#pragma unroll
          for (int i = 0; i < 7; i++) o[i] = e[i] * inv;
        }
      }
    }
    lds_fence();  // protect lbuf/buf before next iteration
  }
}

__launch_bounds__(256, 5)
__global__ void edgeK(const ushort* __restrict__ xp, const float* __restrict__ xs,
                      const void* dsv, const int* __restrict__ ni,
                      const float* __restrict__ w, const int* __restrict__ flags,
                      void* outv, int n_nodes) {
  __shared__ uint4 sfrag[19 * 64];
  __shared__ ushort sb[4 * 512];
  __shared__ float sl[4 * 128];
  if (threadIdx.x < 64) {
    int ln = threadIdx.x;
    U8 tmp;
#pragma unroll
    for (int t = 0; t < 2; t++) {
      tmp.v = bfrag(w + WOFF_WSUM + 16 * t, 32, 16, 32, 1.f);  sfrag[(0 + t) * 64 + ln] = tmp.u;
#pragma unroll
      for (int k = 0; k < KNB; k++) {
        tmp.v = bfrag(w + WOFF_WE1 + k * 33 * 32 + 16 * t, 32, 16, 32, -1.f);
        sfrag[(2 + k * 2 + t) * 64 + ln] = tmp.u;
      }
      tmp.v = bfrag(w + WOFF_WDSQ + 16 * t, 32, 16, KNB, 1.f); sfrag[(14 + t) * 64 + ln] = tmp.u;
      tmp.v = bfrag(w + WOFF_WE2 + 16 * t, 32, 16, 32, 1.f);   sfrag[(16 + t) * 64 + ln] = tmp.u;
    }
    tmp.v = bfrag(w + WOFF_WE3, 6, 6, 32, 1.f); sfrag[18 * 64 + ln] = tmp.u;
  }
  __syncthreads();
  ushort* buf = sb + (threadIdx.x >> 6) * 512;
  float* lbuf = sl + (threadIdx.x >> 6) * 128;
  if (flags[0]) edge_tiles<true>(xp, xs, dsv, ni, flags[1], w, outv, n_nodes, sfrag, buf, lbuf);
  else          edge_tiles<false>(xp, xs, dsv, ni, flags[1], w, outv, n_nodes, sfrag, buf, lbuf);
}

// ==================== fallback path (small ws) ====================
template <bool BF16>
__device__ __forceinline__ float wval(const void* W, long i) {
  if (BF16) return b2f(((const bf16*)W)[i]);
  return ((const float*)W)[i];
}

__device__ __forceinline__ void block_flags(const ushort* xb, const int* ni, int* sflags) {
  if (threadIdx.x < 64) {
    int t = threadIdx.x;
    int bad = 0;
    for (int i = t; i < 256; i += 64) {
      float v = __uint_as_float(((unsigned)xb[i]) << 16);
      if (!(fabsf(v) < 100.f)) bad++;
    }
    unsigned long long bm = __ballot(bad > 0);
    unsigned long long hm = __ballot(ni[2 * t + 1] != 0);
    if (t == 0) {
      sflags[0] = (__popcll(bm) < 4) ? 1 : 0;
      sflags[1] = (hm == 0ULL) ? 1 : 0;
    }
  }
  __syncthreads();
}

template <bool BF16>
__device__ void node_body(int n, int n_nodes, const void* xv, const void* dsv,
                          const int* __restrict__ ni, int i64,
                          const void* Wp, const void* bp, const void* We1, const void* be1,
                          const void* We2, const void* be2, const void* We3, const void* be3,
                          const void* Ws1, const void* bs1, const void* Ws2, const void* bs2,
                          const void* Ws3, const void* bs3, void* outv) {
  float h[32], s1[32];
#pragma unroll
  for (int o = 0; o < 32; o++) { h[o] = wval<BF16>(bp, o); s1[o] = wval<BF16>(bs1, o); }
  for (int j = 0; j < F_IN; j++) {
    float xj = wval<BF16>(xv, (long)n * F_IN + j);
#pragma unroll
    for (int o = 0; o < 32; o++) {
      h[o]  += xj * wval<BF16>(Wp,  (long)j * 32 + o);
      s1[o] += xj * wval<BF16>(Ws1, (long)j * 32 + o);
    }
  }
  float own[32];
#pragma unroll
  for (int o = 0; o < 32; o++) own[o] = eluf(h[o]);
  float s2[32];
#pragma unroll
  for (int o = 0; o < 32; o++) s2[o] = wval<BF16>(bs2, o);
  for (int j = 0; j < 32; j++) {
    float v = eluf(s1[j]);
#pragma unroll
    for (int o = 0; o < 32; o++) s2[o] += v * wval<BF16>(Ws2, (long)j * 32 + o);
  }
  float xsv = wval<BF16>(bs3, 0);
#pragma unroll
  for (int j = 0; j < 32; j++) xsv += eluf(s2[j]) * wval<BF16>(Ws3, j);

  float h1[32];
#pragma unroll
  for (int o = 0; o < 32; o++) h1[o] = wval<BF16>(be1, o);
  for (int k = 0; k < KNB; k++) {
    long pos = (long)n * KNB + k;
    int idx = i64 ? ni[2 * pos] : ni[pos];
    float mmask = idx < 0 ? 0.f : 1.f;
    long ai = idx < 0 ? 0 : idx;
    if (ai >= n_nodes) ai = 0;
    float nh[32];
#pragma unroll
    for (int o = 0; o < 32; o++) nh[o] = wval<BF16>(bp, o);
    for (int j = 0; j < F_IN; j++) {
      float xj = wval<BF16>(xv, ai * F_IN + j);
#pragma unroll
      for (int o = 0; o < 32; o++) nh[o] += xj * wval<BF16>(Wp, (long)j * 32 + o);
    }
#pragma unroll
    for (int j = 0; j < 32; j++) {
      float d = own[j] - mmask * eluf(nh[j]);
#pragma unroll
      for (int o = 0; o < 32; o++) h1[o] += d * wval<BF16>(We1, ((long)(k * 33 + j)) * 32 + o);
    }
    float dsq = BF16 ? b2f(((const bf16*)dsv)[pos]) : ((const float*)dsv)[pos];
#pragma unroll
    for (int o = 0; o < 32; o++) h1[o] += dsq * wval<BF16>(We1, ((long)(k * 33 + 32)) * 32 + o);
  }
  float h2[32];
#pragma unroll
  for (int o = 0; o < 32; o++) h2[o] = wval<BF16>(be2, o);
  for (int j = 0; j < 32; j++) {
    float v = eluf(h1[j]);
#pragma unroll
    for (int o = 0; o < 32; o++) h2[o] += v * wval<BF16>(We2, (long)j * 32 + o);
  }
  float lg[7];
  lg[0] = xsv;
#pragma unroll
  for (int o = 0; o < 6; o++) lg[1 + o] = wval<BF16>(be3, o);
  for (int j = 0; j < 32; j++) {
    float v = eluf(h2[j]);
#pragma unroll
    for (int o = 0; o < 6; o++) lg[1 + o] += v * wval<BF16>(We3, (long)j * 6 + o);
  }
  float mx = lg[0];
#pragma unroll
  for (int i = 1; i < 7; i++) mx = fmaxf(mx, lg[i]);
  float e[7], ssum = 0.f;
#pragma unroll
  for (int i = 0; i < 7; i++) { e[i] = __expf(lg[i] - mx); ssum += e[i]; }
  float inv = 1.f / ssum;
  if (BF16) {
    bf16* o = (bf16*)outv;
#pragma unroll
    for (int i = 0; i < 7; i++) o[(long)n * 7 + i] = __float2bfloat16(e[i] * inv);
  } else {
    float* o = (float*)outv;
#pragma unroll
    for (int i = 0; i < 7; i++) o[(long)n * 7 + i] = e[i] * inv;
  }
}

__launch_bounds__(256)
__global__ void fused(const void* xv, const void* dsv, const int* __restrict__ ni,
                      const void* Wp, const void* bp, const void* We1, const void* be1,
                      const void* We2, const void* be2, const void* We3, const void* be3,
                      const void* Ws1, const void* bs1, const void* Ws2, const void* bs2,
                      const void* Ws3, const void* bs3, void* outv, int n_nodes) {
  __shared__ int sflags[2];
  block_flags((const ushort*)xv, ni, sflags);
  int n = blockIdx.x * blockDim.x + threadIdx.x;
  if (n >= n_nodes) return;
  if (sflags[0]) node_body<true>(n, n_nodes, xv, dsv, ni, sflags[1], Wp, bp, We1, be1,
                                 We2, be2, We3, be3, Ws1, bs1, Ws2, bs2, Ws3, bs3, outv);
  else           node_body<false>(n, n_nodes, xv, dsv, ni, sflags[1], Wp, bp, We1, be1,
                                  We2, be2, We3, be3, Ws1, bs1, Ws2, bs2, Ws3, bs3, outv);
}

extern "C" void kernel_launch(void* const* d_in, const int* in_sizes, int n_in,
                              void* d_out, int out_size, void* d_ws, size_t ws_size,
                              hipStream_t stream) {
  const void* x      = d_in[0];
  const void* distsq = d_in[1];
  const int*  nidx   = (const int*)d_in[2];

  float* w = (float*)d_ws;
  int* flags = (int*)(w + FLAGS_OFF);
  int n_nodes = in_sizes[0] / F_IN;

  size_t need = (size_t)STAGE_OFF * 4 + (size_t)n_nodes * 64 + (size_t)n_nodes * 4 + 256;
  if (ws_size >= need) {
    setupK<<<1, 256, 0, stream>>>((const ushort*)x, nidx,
                                  d_in[3], d_in[4], d_in[5], d_in[6], d_in[7], d_in[8],
                                  d_in[9], d_in[10], d_in[11], d_in[12], d_in[13], d_in[14],
                                  d_in[15], d_in[16], w);
    ushort* xp = (ushort*)(w + STAGE_OFF);
    float* xs = (float*)(xp + (size_t)n_nodes * 32);
    preK<<<2048, 256, 0, stream>>>(x, w, flags, xp, xs, n_nodes);
    edgeK<<<2048, 256, 0, stream>>>(xp, xs, distsq, nidx, w, flags, d_out, n_nodes);
  } else {
    int grid = (n_nodes + 255) / 256;
    fused<<<grid, 256, 0, stream>>>(x, distsq, nidx, d_in[3], d_in[4], d_in[5], d_in[6],
                                    d_in[7], d_in[8], d_in[9], d_in[10], d_in[11], d_in[12],
                                    d_in[13], d_in[14], d_in[15], d_in[16], d_out, n_nodes);
  }
}

// Round 8
// 294.898 us; speedup vs baseline: 1.4973x; 1.4973x over previous
//
#include <hip/hip_runtime.h>
#include <hip/hip_bf16.h>
#include <math.h>

typedef __hip_bfloat16 bf16;
typedef __attribute__((ext_vector_type(8))) __bf16 bf16x8;
typedef __attribute__((ext_vector_type(4))) float f32x4;

#define F_IN 64
#define KNB 6

// ws float offsets (fp32 weights + flags); staged xp/xs start at float 16384
#define WOFF_WP   0      // 2048
#define WOFF_BP   2048   // 32
#define WOFF_WE1  2080   // 6336
#define WOFF_BE1  8416   // 32
#define WOFF_WE2  8448   // 1024
#define WOFF_BE2  9472   // 32
#define WOFF_WE3  9504   // 192
#define WOFF_BE3  9696   // 6
#define WOFF_WS1  9728   // 2048
#define WOFF_BS1  11776  // 32
#define WOFF_WS2  11808  // 1024
#define WOFF_BS2  12832  // 32
#define WOFF_WS3  12864  // 32
#define WOFF_BS3  12896  // 1
#define FLAGS_OFF 13056  // int[2]: {is_bf16, is_int64}
#define WOFF_WSUM 13312  // 1024
#define WOFF_WDSQ 14336  // 192
#define STAGE_OFF 16384  // floats; then xp bf16 rows, then xs fp32

__device__ __forceinline__ float b2f(bf16 v) { return __bfloat162float(v); }
// fast ELU via hardware exp; abs err ~1e-7 near 0, far under tol
__device__ __forceinline__ float eluf(float v) { return v > 0.f ? v : __expf(v) - 1.f; }

__device__ __forceinline__ ushort f2bu(float v) {
  __bf16 b = (__bf16)v; ushort u; __builtin_memcpy(&u, &b, 2); return u;
}

union U8 { uint4 u; bf16x8 v; ushort s[8]; };

// wave-private LDS write->read fence: wait lgkmcnt(0) only (keep vmcnt in flight)
__device__ __forceinline__ void lds_fence() {
  __builtin_amdgcn_wave_barrier();
  __builtin_amdgcn_s_waitcnt(0xC07F);
  __builtin_amdgcn_wave_barrier();
}

// ==================== setup: flags + weight staging + derived weights ====================
__global__ void setupK(const ushort* xb, const int* ni,
                       const void* Wp, const void* bp, const void* We1, const void* be1,
                       const void* We2, const void* be2, const void* We3, const void* be3,
                       const void* Ws1, const void* bs1, const void* Ws2, const void* bs2,
                       const void* Ws3, const void* bs3, float* w) {
  __shared__ int sbf;
  int t = threadIdx.x;
  if (t < 64) {
    // fp32 bits read as bf16 pairs -> ~47% of halves are |v|>100 or NaN; bf16 N(0,1) never
    int bad = 0;
    for (int i = t; i < 256; i += 64) {
      float v = __uint_as_float(((unsigned)xb[i]) << 16);
      if (!(fabsf(v) < 100.f)) bad++;
    }
    unsigned long long bm = __ballot(bad > 0);
    unsigned long long hm = __ballot(ni[2 * t + 1] != 0);
    if (t == 0) {
      int isbf = (__popcll(bm) < 4) ? 1 : 0;
      ((int*)(w + FLAGS_OFF))[0] = isbf;
      ((int*)(w + FLAGS_OFF))[1] = (hm == 0ULL) ? 1 : 0;
      sbf = isbf;
    }
  }
  __syncthreads();
  int bf = sbf;
  const void* srcs[14] = {Wp, bp, We1, be1, We2, be2, We3, be3, Ws1, bs1, Ws2, bs2, Ws3, bs3};
  const int sizes[14] = {2048, 32, 6336, 32, 1024, 32, 192, 6, 2048, 32, 1024, 32, 32, 1};
  const int offs[14] = {WOFF_WP, WOFF_BP, WOFF_WE1, WOFF_BE1, WOFF_WE2, WOFF_BE2, WOFF_WE3,
                        WOFF_BE3, WOFF_WS1, WOFF_BS1, WOFF_WS2, WOFF_BS2, WOFF_WS3, WOFF_BS3};
  for (int tt = 0; tt < 14; tt++) {
    const void* s = srcs[tt];
    int nel = sizes[tt];
    float* d = w + offs[tt];
    for (int i = t; i < nel; i += blockDim.x)
      d[i] = bf ? b2f(((const bf16*)s)[i]) : ((const float*)s)[i];
  }
  __syncthreads();
  for (int i = t; i < 1024; i += blockDim.x) {
    int j = i >> 5, o = i & 31;
    float s = 0.f;
    for (int k = 0; k < KNB; k++) s += w[WOFF_WE1 + (k * 33 + j) * 32 + o];
    w[WOFF_WSUM + i] = s;
  }
  for (int i = t; i < 192; i += blockDim.x) {
    int k = i >> 5, o = i & 31;
    w[WOFF_WDSQ + i] = w[WOFF_WE1 + (k * 33 + 32) * 32 + o];
  }
}

// B-fragment builder (fp32 ws): lane(n=lane&15) holds B[k=quad*8+j][n] = sgn*W[k*ld+n]
__device__ __forceinline__ bf16x8 bfrag(const float* W, int ld, int nValid, int kValid, float sgn) {
  int lane = threadIdx.x & 63;
  int n = lane & 15, quad = lane >> 4;
  bf16x8 r;
#pragma unroll
  for (int j = 0; j < 8; j++) {
    int k = quad * 8 + j;
    float v = (n < nValid && k < kValid) ? sgn * W[k * ld + n] : 0.f;
    r[j] = (__bf16)v;
  }
  return r;
}

// A-fragment from a 64-wide feature row: lane(m=lane&15) holds row[k0+quad*8+j]
template <bool BF16>
__device__ __forceinline__ bf16x8 afrag_row(const void* base, long row, int k0) {
  int quad = (threadIdx.x & 63) >> 4;
  if (BF16) {
    U8 u;
    u.u = *(const uint4*)((const ushort*)base + row * F_IN + k0 + quad * 8);
    return u.v;
  } else {
    const float* p = (const float*)base + row * F_IN + k0 + quad * 8;
    float4 a = *(const float4*)p, b = *(const float4*)(p + 4);
    bf16x8 r;
    r[0] = (__bf16)a.x; r[1] = (__bf16)a.y; r[2] = (__bf16)a.z; r[3] = (__bf16)a.w;
    r[4] = (__bf16)b.x; r[5] = (__bf16)b.y; r[6] = (__bf16)b.z; r[7] = (__bf16)b.w;
    return r;
  }
}

// ==================== kernel A: pre-dense + self MLP (MFMA, r4 body) ====================
template <bool BF16>
__device__ void pre_tiles(const void* xv, const float* __restrict__ w,
                          ushort* __restrict__ xp, float* __restrict__ xs,
                          int n_nodes, ushort* buf) {
  int lane = threadIdx.x & 63;
  int m = lane & 15, quad = lane >> 4;

  bf16x8 fwp[2][2], fws1[2][2], fws2[2], fws3;
#pragma unroll
  for (int s = 0; s < 2; s++)
#pragma unroll
    for (int t = 0; t < 2; t++) {
      fwp[s][t]  = bfrag(w + WOFF_WP  + s * 32 * 32 + 16 * t, 32, 16, 32, 1.f);
      fws1[s][t] = bfrag(w + WOFF_WS1 + s * 32 * 32 + 16 * t, 32, 16, 32, 1.f);
    }
#pragma unroll
  for (int t = 0; t < 2; t++) fws2[t] = bfrag(w + WOFF_WS2 + 16 * t, 32, 16, 32, 1.f);
  fws3 = bfrag(w + WOFF_WS3, 1, 1, 32, 1.f);
  float bpv[2], bs1v[2], bs2v[2];
#pragma unroll
  for (int t = 0; t < 2; t++) {
    bpv[t]  = w[WOFF_BP  + m + 16 * t];
    bs1v[t] = w[WOFF_BS1 + m + 16 * t];
    bs2v[t] = w[WOFF_BS2 + m + 16 * t];
  }
  float bs3f = w[WOFF_BS3];

  int T = (n_nodes + 15) >> 4;
  int wid = (int)((blockIdx.x * blockDim.x + threadIdx.x) >> 6);
  int nw = (int)((gridDim.x * blockDim.x) >> 6);
  f32x4 zero = {0.f, 0.f, 0.f, 0.f};

  for (int t0 = wid; t0 < T; t0 += nw) {
    long n0 = (long)t0 * 16;
    long row = n0 + m; if (row >= n_nodes) row = n_nodes - 1;
    bf16x8 a0 = afrag_row<BF16>(xv, row, 0);
    bf16x8 a1 = afrag_row<BF16>(xv, row, 32);
    f32x4 accp[2], accs[2];
#pragma unroll
    for (int t = 0; t < 2; t++) {
      accp[t] = __builtin_amdgcn_mfma_f32_16x16x32_bf16(a0, fwp[0][t], zero, 0, 0, 0);
      accp[t] = __builtin_amdgcn_mfma_f32_16x16x32_bf16(a1, fwp[1][t], accp[t], 0, 0, 0);
      accs[t] = __builtin_amdgcn_mfma_f32_16x16x32_bf16(a0, fws1[0][t], zero, 0, 0, 0);
      accs[t] = __builtin_amdgcn_mfma_f32_16x16x32_bf16(a1, fws1[1][t], accs[t], 0, 0, 0);
    }
    // xp = elu(pre): C-layout -> LDS bf16 -> row layout -> global
#pragma unroll
    for (int t = 0; t < 2; t++)
#pragma unroll
      for (int r = 0; r < 4; r++)
        buf[(quad * 4 + r) * 32 + m + 16 * t] = f2bu(eluf(accp[t][r] + bpv[t]));
    lds_fence();
    {
      uint4 rv = *(const uint4*)(buf + m * 32 + quad * 8);
      *(uint4*)(xp + row * 32 + quad * 8) = rv;
    }
    // s1 -> LDS -> A-frag
#pragma unroll
    for (int t = 0; t < 2; t++)
#pragma unroll
      for (int r = 0; r < 4; r++)
        buf[(quad * 4 + r) * 32 + m + 16 * t] = f2bu(eluf(accs[t][r] + bs1v[t]));
    lds_fence();
    U8 as1; as1.u = *(const uint4*)(buf + m * 32 + quad * 8);
    f32x4 acc2[2];
#pragma unroll
    for (int t = 0; t < 2; t++)
      acc2[t] = __builtin_amdgcn_mfma_f32_16x16x32_bf16(as1.v, fws2[t], zero, 0, 0, 0);
#pragma unroll
    for (int t = 0; t < 2; t++)
#pragma unroll
      for (int r = 0; r < 4; r++)
        buf[(quad * 4 + r) * 32 + m + 16 * t] = f2bu(eluf(acc2[t][r] + bs2v[t]));
    lds_fence();
    U8 as2; as2.u = *(const uint4*)(buf + m * 32 + quad * 8);
    f32x4 accx = __builtin_amdgcn_mfma_f32_16x16x32_bf16(as2.v, fws3, zero, 0, 0, 0);
    if (m == 0) {
#pragma unroll
      for (int r = 0; r < 4; r++) {
        long orow = n0 + quad * 4 + r;
        if (orow < n_nodes) xs[orow] = accx[r] + bs3f;
      }
    }
    lds_fence();  // protect buf before next iteration overwrites
  }
}

__launch_bounds__(256)
__global__ void preK(const void* xv, const float* __restrict__ w,
                     const int* __restrict__ flags,
                     ushort* __restrict__ xp, float* __restrict__ xs, int n_nodes) {
  __shared__ ushort sb[4 * 512];
  ushort* buf = sb + (threadIdx.x >> 6) * 512;
  if (flags[0]) pre_tiles<true>(xv, w, xp, xs, n_nodes, buf);
  else          pre_tiles<false>(xv, w, xp, xs, n_nodes, buf);
}

// ==================== kernel B: edge MLP + softmax (MFMA, r4 body) ====================
template <bool BF16>
__device__ void edge_tiles(const ushort* __restrict__ xp, const float* __restrict__ xs,
                           const void* dsv, const int* __restrict__ ni, int i64,
                           const float* __restrict__ w, void* outv, int n_nodes,
                           ushort* buf, float* lbuf) {
  int lane = threadIdx.x & 63;
  int m = lane & 15, quad = lane >> 4;

  bf16x8 fsum[2], fwe1[KNB][2], fdsq[2], fwe2[2], fwe3;
#pragma unroll
  for (int t = 0; t < 2; t++) {
    fsum[t] = bfrag(w + WOFF_WSUM + 16 * t, 32, 16, 32, 1.f);
    fdsq[t] = bfrag(w + WOFF_WDSQ + 16 * t, 32, 16, KNB, 1.f);
    fwe2[t] = bfrag(w + WOFF_WE2 + 16 * t, 32, 16, 32, 1.f);
#pragma unroll
    for (int k = 0; k < KNB; k++)
      fwe1[k][t] = bfrag(w + WOFF_WE1 + k * 33 * 32 + 16 * t, 32, 16, 32, -1.f);
  }
  fwe3 = bfrag(w + WOFF_WE3, 6, 6, 32, 1.f);
  float be1v[2], be2v[2];
#pragma unroll
  for (int t = 0; t < 2; t++) {
    be1v[t] = w[WOFF_BE1 + m + 16 * t];
    be2v[t] = w[WOFF_BE2 + m + 16 * t];
  }
  float be3v = (m < 6) ? w[WOFF_BE3 + m] : 0.f;

  int T = (n_nodes + 15) >> 4;
  int wid = (int)((blockIdx.x * blockDim.x + threadIdx.x) >> 6);
  int nw = (int)((gridDim.x * blockDim.x) >> 6);
  f32x4 zero = {0.f, 0.f, 0.f, 0.f};

  for (int t0 = wid; t0 < T; t0 += nw) {
    long n0 = (long)t0 * 16;
    long row = n0 + m; if (row >= n_nodes) row = n_nodes - 1;

    int idxs[KNB];
#pragma unroll
    for (int k = 0; k < KNB; k++)
      idxs[k] = i64 ? ni[(row * KNB + k) * 2] : ni[row * KNB + k];

    U8 own; own.u = *(const uint4*)(xp + row * 32 + quad * 8);
    U8 nb[KNB];
#pragma unroll
    for (int k = 0; k < KNB; k++) {
      long ai = idxs[k];
      if (ai < 0 || ai >= n_nodes) ai = 0;
      nb[k].u = *(const uint4*)(xp + ai * 32 + quad * 8);
      if (idxs[k] < 0) { nb[k].u.x = 0; nb[k].u.y = 0; nb[k].u.z = 0; nb[k].u.w = 0; }
    }

    // dsq A-frag: A[m][k]=distsq[m][k] (k<6); only quad 0 holds data
    U8 ad; ad.u.x = 0; ad.u.y = 0; ad.u.z = 0; ad.u.w = 0;
    if (quad == 0) {
      if (BF16) {
        const unsigned* dp = (const unsigned*)dsv;
        ad.u.x = dp[row * 3 + 0];
        ad.u.y = dp[row * 3 + 1];
        ad.u.z = dp[row * 3 + 2];
      } else {
        const float* dp = (const float*)dsv + row * KNB;
#pragma unroll
        for (int k = 0; k < KNB; k++) ad.s[k] = f2bu(dp[k]);
      }
    }
    float xsv = xs[row];

    // h1 = -sum_k nb_k@Wk + dsq@Wdsq + own@Wsum
    f32x4 accA[2], accB[2];
#pragma unroll
    for (int t = 0; t < 2; t++) {
      accA[t] = __builtin_amdgcn_mfma_f32_16x16x32_bf16(nb[0].v, fwe1[0][t], zero, 0, 0, 0);
      accA[t] = __builtin_amdgcn_mfma_f32_16x16x32_bf16(nb[1].v, fwe1[1][t], accA[t], 0, 0, 0);
      accA[t] = __builtin_amdgcn_mfma_f32_16x16x32_bf16(nb[2].v, fwe1[2][t], accA[t], 0, 0, 0);
      accB[t] = __builtin_amdgcn_mfma_f32_16x16x32_bf16(nb[3].v, fwe1[3][t], zero, 0, 0, 0);
      accB[t] = __builtin_amdgcn_mfma_f32_16x16x32_bf16(nb[4].v, fwe1[4][t], accB[t], 0, 0, 0);
      accB[t] = __builtin_amdgcn_mfma_f32_16x16x32_bf16(nb[5].v, fwe1[5][t], accB[t], 0, 0, 0);
      accB[t] = __builtin_amdgcn_mfma_f32_16x16x32_bf16(ad.v, fdsq[t], accB[t], 0, 0, 0);
      accA[t] = __builtin_amdgcn_mfma_f32_16x16x32_bf16(own.v, fsum[t], accA[t], 0, 0, 0);
    }

    // elu -> LDS -> A-frag
#pragma unroll
    for (int t = 0; t < 2; t++)
#pragma unroll
      for (int r = 0; r < 4; r++)
        buf[(quad * 4 + r) * 32 + m + 16 * t] =
            f2bu(eluf(accA[t][r] + accB[t][r] + be1v[t]));
    lds_fence();
    U8 a1; a1.u = *(const uint4*)(buf + m * 32 + quad * 8);
    f32x4 acc2[2];
#pragma unroll
    for (int t = 0; t < 2; t++)
      acc2[t] = __builtin_amdgcn_mfma_f32_16x16x32_bf16(a1.v, fwe2[t], zero, 0, 0, 0);
#pragma unroll
    for (int t = 0; t < 2; t++)
#pragma unroll
      for (int r = 0; r < 4; r++)
        buf[(quad * 4 + r) * 32 + m + 16 * t] = f2bu(eluf(acc2[t][r] + be2v[t]));
    lds_fence();
    U8 a2; a2.u = *(const uint4*)(buf + m * 32 + quad * 8);
    f32x4 acc3 = __builtin_amdgcn_mfma_f32_16x16x32_bf16(a2.v, fwe3, zero, 0, 0, 0);

    if (m < 6) {
#pragma unroll
      for (int r = 0; r < 4; r++) lbuf[(quad * 4 + r) * 8 + m] = acc3[r] + be3v;
    }
    lds_fence();
    if (lane < 16) {
      long nodeid = n0 + lane;
      if (nodeid < n_nodes) {
        float lg[7];
        lg[0] = xsv;  // row == nodeid for lanes 0..15
#pragma unroll
        for (int i = 0; i < 6; i++) lg[1 + i] = lbuf[lane * 8 + i];
        float mx = lg[0];
#pragma unroll
        for (int i = 1; i < 7; i++) mx = fmaxf(mx, lg[i]);
        float e[7], ssum = 0.f;
#pragma unroll
        for (int i = 0; i < 7; i++) { e[i] = __expf(lg[i] - mx); ssum += e[i]; }
        float inv = 1.f / ssum;
        if (BF16) {
          ushort* o = (ushort*)outv + nodeid * 7;
#pragma unroll
          for (int i = 0; i < 7; i++) o[i] = f2bu(e[i] * inv);
        } else {
          float* o = (float*)outv + nodeid * 7;
#pragma unroll
          for (int i = 0; i < 7; i++) o[i] = e[i] * inv;
        }
      }
    }
    lds_fence();  // protect lbuf/buf before next iteration
  }
}

__launch_bounds__(256)
__global__ void edgeK(const ushort* __restrict__ xp, const float* __restrict__ xs,
                      const void* dsv, const int* __restrict__ ni,
                      const float* __restrict__ w, const int* __restrict__ flags,
                      void* outv, int n_nodes) {
  __shared__ ushort sb[4 * 512];
  __shared__ float sl[4 * 128];
  ushort* buf = sb + (threadIdx.x >> 6) * 512;
  float* lbuf = sl + (threadIdx.x >> 6) * 128;
  if (flags[0]) edge_tiles<true>(xp, xs, dsv, ni, flags[1], w, outv, n_nodes, buf, lbuf);
  else          edge_tiles<false>(xp, xs, dsv, ni, flags[1], w, outv, n_nodes, buf, lbuf);
}

// ==================== fallback path (small ws) ====================
template <bool BF16>
__device__ __forceinline__ float wval(const void* W, long i) {
  if (BF16) return b2f(((const bf16*)W)[i]);
  return ((const float*)W)[i];
}

__device__ __forceinline__ void block_flags(const ushort* xb, const int* ni, int* sflags) {
  if (threadIdx.x < 64) {
    int t = threadIdx.x;
    int bad = 0;
    for (int i = t; i < 256; i += 64) {
      float v = __uint_as_float(((unsigned)xb[i]) << 16);
      if (!(fabsf(v) < 100.f)) bad++;
    }
    unsigned long long bm = __ballot(bad > 0);
    unsigned long long hm = __ballot(ni[2 * t + 1] != 0);
    if (t == 0) {
      sflags[0] = (__popcll(bm) < 4) ? 1 : 0;
      sflags[1] = (hm == 0ULL) ? 1 : 0;
    }
  }
  __syncthreads();
}

template <bool BF16>
__device__ void node_body(int n, int n_nodes, const void* xv, const void* dsv,
                          const int* __restrict__ ni, int i64,
                          const void* Wp, const void* bp, const void* We1, const void* be1,
                          const void* We2, const void* be2, const void* We3, const void* be3,
                          const void* Ws1, const void* bs1, const void* Ws2, const void* bs2,
                          const void* Ws3, const void* bs3, void* outv) {
  float h[32], s1[32];
#pragma unroll
  for (int o = 0; o < 32; o++) { h[o] = wval<BF16>(bp, o); s1[o] = wval<BF16>(bs1, o); }
  for (int j = 0; j < F_IN; j++) {
    float xj = wval<BF16>(xv, (long)n * F_IN + j);
#pragma unroll
    for (int o = 0; o < 32; o++) {
      h[o]  += xj * wval<BF16>(Wp,  (long)j * 32 + o);
      s1[o] += xj * wval<BF16>(Ws1, (long)j * 32 + o);
    }
  }
  float own[32];
#pragma unroll
  for (int o = 0; o < 32; o++) own[o] = eluf(h[o]);
  float s2[32];
#pragma unroll
  for (int o = 0; o < 32; o++) s2[o] = wval<BF16>(bs2, o);
  for (int j = 0; j < 32; j++) {
    float v = eluf(s1[j]);
#pragma unroll
    for (int o = 0; o < 32; o++) s2[o] += v * wval<BF16>(Ws2, (long)j * 32 + o);
  }
  float xsv = wval<BF16>(bs3, 0);
#pragma unroll
  for (int j = 0; j < 32; j++) xsv += eluf(s2[j]) * wval<BF16>(Ws3, j);

  float h1[32];
#pragma unroll
  for (int o = 0; o < 32; o++) h1[o] = wval<BF16>(be1, o);
  for (int k = 0; k < KNB; k++) {
    long pos = (long)n * KNB + k;
    int idx = i64 ? ni[2 * pos] : ni[pos];
    float mmask = idx < 0 ? 0.f : 1.f;
    long ai = idx < 0 ? 0 : idx;
    if (ai >= n_nodes) ai = 0;
    float nh[32];
#pragma unroll
    for (int o = 0; o < 32; o++) nh[o] = wval<BF16>(bp, o);
    for (int j = 0; j < F_IN; j++) {
      float xj = wval<BF16>(xv, ai * F_IN + j);
#pragma unroll
      for (int o = 0; o < 32; o++) nh[o] += xj * wval<BF16>(Wp, (long)j * 32 + o);
    }
#pragma unroll
    for (int j = 0; j < 32; j++) {
      float d = own[j] - mmask * eluf(nh[j]);
#pragma unroll
      for (int o = 0; o < 32; o++) h1[o] += d * wval<BF16>(We1, ((long)(k * 33 + j)) * 32 + o);
    }
    float dsq = BF16 ? b2f(((const bf16*)dsv)[pos]) : ((const float*)dsv)[pos];
#pragma unroll
    for (int o = 0; o < 32; o++) h1[o] += dsq * wval<BF16>(We1, ((long)(k * 33 + 32)) * 32 + o);
  }
  float h2[32];
#pragma unroll
  for (int o = 0; o < 32; o++) h2[o] = wval<BF16>(be2, o);
  for (int j = 0; j < 32; j++) {
    float v = eluf(h1[j]);
#pragma unroll
    for (int o = 0; o < 32; o++) h2[o] += v * wval<BF16>(We2, (long)j * 32 + o);
  }
  float lg[7];
  lg[0] = xsv;
#pragma unroll
  for (int o = 0; o < 6; o++) lg[1 + o] = wval<BF16>(be3, o);
  for (int j = 0; j < 32; j++) {
    float v = eluf(h2[j]);
#pragma unroll
    for (int o = 0; o < 6; o++) lg[1 + o] += v * wval<BF16>(We3, (long)j * 6 + o);
  }
  float mx = lg[0];
#pragma unroll
  for (int i = 1; i < 7; i++) mx = fmaxf(mx, lg[i]);
  float e[7], ssum = 0.f;
#pragma unroll
  for (int i = 0; i < 7; i++) { e[i] = __expf(lg[i] - mx); ssum += e[i]; }
  float inv = 1.f / ssum;
  if (BF16) {
    bf16* o = (bf16*)outv;
#pragma unroll
    for (int i = 0; i < 7; i++) o[(long)n * 7 + i] = __float2bfloat16(e[i] * inv);
  } else {
    float* o = (float*)outv;
#pragma unroll
    for (int i = 0; i < 7; i++) o[(long)n * 7 + i] = e[i] * inv;
  }
}

__launch_bounds__(256)
__global__ void fused(const void* xv, const void* dsv, const int* __restrict__ ni,
                      const void* Wp, const void* bp, const void* We1, const void* be1,
                      const void* We2, const void* be2, const void* We3, const void* be3,
                      const void* Ws1, const void* bs1, const void* Ws2, const void* bs2,
                      const void* Ws3, const void* bs3, void* outv, int n_nodes) {
  __shared__ int sflags[2];
  block_flags((const ushort*)xv, ni, sflags);
  int n = blockIdx.x * blockDim.x + threadIdx.x;
  if (n >= n_nodes) return;
  if (sflags[0]) node_body<true>(n, n_nodes, xv, dsv, ni, sflags[1], Wp, bp, We1, be1,
                                 We2, be2, We3, be3, Ws1, bs1, Ws2, bs2, Ws3, bs3, outv);
  else           node_body<false>(n, n_nodes, xv, dsv, ni, sflags[1], Wp, bp, We1, be1,
                                  We2, be2, We3, be3, Ws1, bs1, Ws2, bs2, Ws3, bs3, outv);
}

extern "C" void kernel_launch(void* const* d_in, const int* in_sizes, int n_in,
                              void* d_out, int out_size, void* d_ws, size_t ws_size,
                              hipStream_t stream) {
  const void* x      = d_in[0];
  const void* distsq = d_in[1];
  const int*  nidx   = (const int*)d_in[2];

  float* w = (float*)d_ws;
  int* flags = (int*)(w + FLAGS_OFF);
  int n_nodes = in_sizes[0] / F_IN;

  size_t need = (size_t)STAGE_OFF * 4 + (size_t)n_nodes * 64 + (size_t)n_nodes * 4 + 256;
  if (ws_size >= need) {
    setupK<<<1, 256, 0, stream>>>((const ushort*)x, nidx,
                                  d_in[3], d_in[4], d_in[5], d_in[6], d_in[7], d_in[8],
                                  d_in[9], d_in[10], d_in[11], d_in[12], d_in[13], d_in[14],
                                  d_in[15], d_in[16], w);
    ushort* xp = (ushort*)(w + STAGE_OFF);
    float* xs = (float*)(xp + (size_t)n_nodes * 32);
    preK<<<1024, 256, 0, stream>>>(x, w, flags, xp, xs, n_nodes);
    edgeK<<<1024, 256, 0, stream>>>(xp, xs, distsq, nidx, w, flags, d_out, n_nodes);
  } else {
    int grid = (n_nodes + 255) / 256;
    fused<<<grid, 256, 0, stream>>>(x, distsq, nidx, d_in[3], d_in[4], d_in[5], d_in[6],
                                    d_in[7], d_in[8], d_in[9], d_in[10], d_in[11], d_in[12],
                                    d_in[13], d_in[14], d_in[15], d_in[16], d_out, n_nodes);
  }
}